// Round 2
// baseline (295.582 us; speedup 1.0000x reference)
//
#include <hip/hip_runtime.h>

// PositionalSparseLinear2d: out[b,o] = sum_k input[b, conn[o,k]] * weights[o,k]
// B=64, N_in = N_out = 512*512 = 262144, K=8, all fp32.

#define IN_N  (512*512)
#define OUT_N (512*512)
#define BATCH 64
#define KCONN 8

// ---------------------------------------------------------------------------
// Kernel 1: transpose input (BATCH, IN_N) -> x_t (IN_N, BATCH) so the batch
// dimension is contiguous (one idx-row = 64 floats = 256 B = 4 full cache
// lines). Classic LDS-tiled transpose, 64x64 tile, float4 on both sides.
// ---------------------------------------------------------------------------
__global__ __launch_bounds__(256) void transpose_kernel(const float* __restrict__ in,
                                                        float* __restrict__ xt) {
    __shared__ float lds[64][65];   // +1 pad: column reads conflict-free
    const int t    = threadIdx.x;
    const int idx0 = blockIdx.x * 64;
    const int tr   = t >> 4;         // 0..15
    const int tc   = (t & 15) << 2;  // 0,4,...,60

#pragma unroll
    for (int p = 0; p < 4; ++p) {
        const int b = tr + p * 16;   // batch row
        float4 v = *(const float4*)(in + (size_t)b * IN_N + idx0 + tc);
        lds[b][tc + 0] = v.x;
        lds[b][tc + 1] = v.y;
        lds[b][tc + 2] = v.z;
        lds[b][tc + 3] = v.w;
    }
    __syncthreads();
#pragma unroll
    for (int p = 0; p < 4; ++p) {
        const int ii = tr + p * 16;  // idx within tile
        float4 u;
        u.x = lds[tc + 0][ii];
        u.y = lds[tc + 1][ii];
        u.z = lds[tc + 2][ii];
        u.w = lds[tc + 3][ii];
        *(float4*)(xt + (size_t)(idx0 + ii) * BATCH + tc) = u;
    }
}

// ---------------------------------------------------------------------------
// Kernel 2: gather + weighted sum on the transposed layout, MLP-maximized.
// Thread owns one output o and a 16-batch quarter (blockIdx.y in 0..3):
// per connection k it reads exactly ONE 64 B cache line (4 float4) -- 100%
// line utilization. All 32 float4 loads are issued before any FMA so ~32
// loads/wave are in flight (vs ~4 in the previous register-starved version).
// ---------------------------------------------------------------------------
__global__ __launch_bounds__(256) void gather_kernel(const float* __restrict__ xt,
                                                     const int* __restrict__ conn,
                                                     const float* __restrict__ w,
                                                     float* __restrict__ out) {
    const int o = blockIdx.x * 256 + threadIdx.x;
    const int h = blockIdx.y * 16;   // batch quarter offset: 0,16,32,48

    const int4   c0 = ((const int4*)conn)[(size_t)o * 2 + 0];
    const int4   c1 = ((const int4*)conn)[(size_t)o * 2 + 1];
    const float4 w0 = ((const float4*)w)[(size_t)o * 2 + 0];
    const float4 w1 = ((const float4*)w)[(size_t)o * 2 + 1];

    const int   cidx[KCONN] = {c0.x, c0.y, c0.z, c0.w, c1.x, c1.y, c1.z, c1.w};
    const float wk[KCONN]   = {w0.x, w0.y, w0.z, w0.w, w1.x, w1.y, w1.z, w1.w};

    // Issue all 32 independent line-loads first: max memory-level parallelism.
    float4 v[KCONN * 4];
#pragma unroll
    for (int k = 0; k < KCONN; ++k) {
        const float4* row = (const float4*)(xt + (size_t)cidx[k] * BATCH + h);
#pragma unroll
        for (int q = 0; q < 4; ++q) v[k * 4 + q] = row[q];
    }

    float acc[16];
#pragma unroll
    for (int b = 0; b < 16; ++b) acc[b] = 0.0f;

#pragma unroll
    for (int k = 0; k < KCONN; ++k) {
        const float wv = wk[k];
#pragma unroll
        for (int q = 0; q < 4; ++q) {
            acc[q * 4 + 0] += v[k * 4 + q].x * wv;
            acc[q * 4 + 1] += v[k * 4 + q].y * wv;
            acc[q * 4 + 2] += v[k * 4 + q].z * wv;
            acc[q * 4 + 3] += v[k * 4 + q].w * wv;
        }
    }

#pragma unroll
    for (int b = 0; b < 16; ++b) {
        out[(size_t)(h + b) * OUT_N + o] = acc[b];   // coalesced across o
    }
}

// ---------------------------------------------------------------------------
// Fallback (only if workspace is too small for the 64 MiB transposed copy):
// direct gather on the original layout. Correct but cache-line-wasteful.
// ---------------------------------------------------------------------------
__global__ __launch_bounds__(256) void direct_kernel(const float* __restrict__ in,
                                                     const int* __restrict__ conn,
                                                     const float* __restrict__ w,
                                                     float* __restrict__ out) {
    const int o = blockIdx.x * 256 + threadIdx.x;

    const int4   c0 = ((const int4*)conn)[(size_t)o * 2 + 0];
    const int4   c1 = ((const int4*)conn)[(size_t)o * 2 + 1];
    const float4 w0 = ((const float4*)w)[(size_t)o * 2 + 0];
    const float4 w1 = ((const float4*)w)[(size_t)o * 2 + 1];

    const int   cidx[KCONN] = {c0.x, c0.y, c0.z, c0.w, c1.x, c1.y, c1.z, c1.w};
    const float wk[KCONN]   = {w0.x, w0.y, w0.z, w0.w, w1.x, w1.y, w1.z, w1.w};

    for (int b = 0; b < BATCH; ++b) {
        const float* xb = in + (size_t)b * IN_N;
        float acc = 0.0f;
#pragma unroll
        for (int k = 0; k < KCONN; ++k) acc += xb[cidx[k]] * wk[k];
        out[(size_t)b * OUT_N + o] = acc;
    }
}

extern "C" void kernel_launch(void* const* d_in, const int* in_sizes, int n_in,
                              void* d_out, int out_size, void* d_ws, size_t ws_size,
                              hipStream_t stream) {
    const float* inp  = (const float*)d_in[0];   // (64, 512, 512) fp32
    const int*   conn = (const int*)d_in[1];     // (262144, 8) int32
    const float* w    = (const float*)d_in[2];   // (262144, 8) fp32
    float*       out  = (float*)d_out;           // (64, 262144) fp32

    const size_t xt_bytes = (size_t)IN_N * BATCH * sizeof(float);  // 64 MiB

    if (ws_size >= xt_bytes) {
        float* xt = (float*)d_ws;
        transpose_kernel<<<IN_N / 64, 256, 0, stream>>>(inp, xt);
        dim3 grid(OUT_N / 256, 4);
        gather_kernel<<<grid, 256, 0, stream>>>(xt, conn, w, out);
    } else {
        direct_kernel<<<OUT_N / 256, 256, 0, stream>>>(inp, conn, w, out);
    }
}

// Round 3
// 225.217 us; speedup vs baseline: 1.3124x; 1.3124x over previous
//
#include <hip/hip_runtime.h>

// PositionalSparseLinear2d: out[b,o] = sum_k input[b, conn[o,k]] * weights[o,k]
// B=64, N_in = N_out = 512*512 = 262144, K=8, all fp32.

#define IN_N  (512*512)
#define OUT_N (512*512)
#define BATCH 64
#define KCONN 8

// ---------------------------------------------------------------------------
// Kernel 1: transpose input (BATCH, IN_N) -> x_t (IN_N, BATCH) so the batch
// dimension is contiguous (one idx-row = 64 floats = 256 B = 4 full cache
// lines). Classic LDS-tiled transpose, 64x64 tile, float4 on both sides.
// ---------------------------------------------------------------------------
__global__ __launch_bounds__(256) void transpose_kernel(const float* __restrict__ in,
                                                        float* __restrict__ xt) {
    __shared__ float lds[64][65];   // +1 pad: column reads conflict-free
    const int t    = threadIdx.x;
    const int idx0 = blockIdx.x * 64;
    const int tr   = t >> 4;         // 0..15 (t>>4 gives 0..15 over 256 threads)
    const int tc   = (t & 15) << 2;  // 0,4,...,60

#pragma unroll
    for (int p = 0; p < 4; ++p) {
        const int b = tr + p * 16;   // batch row
        float4 v = *(const float4*)(in + (size_t)b * IN_N + idx0 + tc);
        lds[b][tc + 0] = v.x;
        lds[b][tc + 1] = v.y;
        lds[b][tc + 2] = v.z;
        lds[b][tc + 3] = v.w;
    }
    __syncthreads();
#pragma unroll
    for (int p = 0; p < 4; ++p) {
        const int ii = tr + p * 16;  // idx within tile
        float4 u;
        u.x = lds[tc + 0][ii];
        u.y = lds[tc + 1][ii];
        u.z = lds[tc + 2][ii];
        u.w = lds[tc + 3][ii];
        *(float4*)(xt + (size_t)(idx0 + ii) * BATCH + tc) = u;
    }
}

// ---------------------------------------------------------------------------
// Kernel 2: K-split gather. Thread = (o, k, 32-batch half). Each thread
// issues 8 independent float4 loads (its 128 B half-row -- 2 adjacent cache
// lines), scales by its weight, then the 8 k-lanes (low 3 bits of the lane
// id) reduce-scatter via __shfl_xor in 3 steps; lane k ends with 4 batch
// sums and stores them. VGPR ~60 -> 32 waves/CU; ~256 loads in flight/CU.
// Reduce-scatter (not butterfly) so final per-lane chunk uses only
// compile-time register indices.
// ---------------------------------------------------------------------------
__global__ __launch_bounds__(256) void gather_kernel(const float* __restrict__ xt,
                                                     const int* __restrict__ conn,
                                                     const float* __restrict__ w,
                                                     float* __restrict__ out) {
    const int t  = threadIdx.x;
    const int o0 = blockIdx.x * 32;          // 32 outputs per block
    const int h  = blockIdx.y * 32;          // batch half: 0 or 32
    const int g  = o0 * KCONN + t;           // coalesced conn/w index
    const int k  = t & 7;
    const int o  = o0 + (t >> 3);

    const int   ci = conn[g];
    const float wv = w[g];

    // 8 independent line-loads: the full 128 B half-row for this (o,k).
    const float4* row = (const float4*)(xt + (size_t)ci * BATCH + h);
    float4 r[8];
#pragma unroll
    for (int q = 0; q < 8; ++q) r[q] = row[q];

    float cur[32];
#pragma unroll
    for (int q = 0; q < 8; ++q) {
        cur[q * 4 + 0] = r[q].x * wv;
        cur[q * 4 + 1] = r[q].y * wv;
        cur[q * 4 + 2] = r[q].z * wv;
        cur[q * 4 + 3] = r[q].w * wv;
    }

    // Reduce-scatter over the 8 k-lanes. After step with mask m (working set
    // n), each lane keeps the half matching its own bit of k; bsel tracks the
    // batch offset of the kept window.
    int bsel = 0;

    // step m=1, n=32
    {
        const bool up = (k & 1) != 0;
        float nxt[16];
#pragma unroll
        for (int j = 0; j < 16; ++j) {
            float send = up ? cur[j] : cur[j + 16];
            float keep = up ? cur[j + 16] : cur[j];
            nxt[j] = keep + __shfl_xor(send, 1, 64);
        }
#pragma unroll
        for (int j = 0; j < 16; ++j) cur[j] = nxt[j];
        if (up) bsel += 16;
    }
    // step m=2, n=16
    {
        const bool up = (k & 2) != 0;
        float nxt[8];
#pragma unroll
        for (int j = 0; j < 8; ++j) {
            float send = up ? cur[j] : cur[j + 8];
            float keep = up ? cur[j + 8] : cur[j];
            nxt[j] = keep + __shfl_xor(send, 2, 64);
        }
#pragma unroll
        for (int j = 0; j < 8; ++j) cur[j] = nxt[j];
        if (up) bsel += 8;
    }
    // step m=4, n=8
    {
        const bool up = (k & 4) != 0;
        float nxt[4];
#pragma unroll
        for (int j = 0; j < 4; ++j) {
            float send = up ? cur[j] : cur[j + 4];
            float keep = up ? cur[j + 4] : cur[j];
            nxt[j] = keep + __shfl_xor(send, 4, 64);
        }
#pragma unroll
        for (int j = 0; j < 4; ++j) cur[j] = nxt[j];
        if (up) bsel += 4;
    }

    // lane holds the full k-sum for batches b = h + bsel + 0..3
#pragma unroll
    for (int j = 0; j < 4; ++j) {
        out[(size_t)(h + bsel + j) * OUT_N + o] = cur[j];
    }
}

// ---------------------------------------------------------------------------
// Fallback (only if workspace is too small for the 64 MiB transposed copy):
// direct gather on the original layout. Correct but cache-line-wasteful.
// ---------------------------------------------------------------------------
__global__ __launch_bounds__(256) void direct_kernel(const float* __restrict__ in,
                                                     const int* __restrict__ conn,
                                                     const float* __restrict__ w,
                                                     float* __restrict__ out) {
    const int o = blockIdx.x * 256 + threadIdx.x;

    const int4   c0 = ((const int4*)conn)[(size_t)o * 2 + 0];
    const int4   c1 = ((const int4*)conn)[(size_t)o * 2 + 1];
    const float4 w0 = ((const float4*)w)[(size_t)o * 2 + 0];
    const float4 w1 = ((const float4*)w)[(size_t)o * 2 + 1];

    const int   cidx[KCONN] = {c0.x, c0.y, c0.z, c0.w, c1.x, c1.y, c1.z, c1.w};
    const float wk[KCONN]   = {w0.x, w0.y, w0.z, w0.w, w1.x, w1.y, w1.z, w1.w};

    for (int b = 0; b < BATCH; ++b) {
        const float* xb = in + (size_t)b * IN_N;
        float acc = 0.0f;
#pragma unroll
        for (int k = 0; k < KCONN; ++k) acc += xb[cidx[k]] * wk[k];
        out[(size_t)b * OUT_N + o] = acc;
    }
}

extern "C" void kernel_launch(void* const* d_in, const int* in_sizes, int n_in,
                              void* d_out, int out_size, void* d_ws, size_t ws_size,
                              hipStream_t stream) {
    const float* inp  = (const float*)d_in[0];   // (64, 512, 512) fp32
    const int*   conn = (const int*)d_in[1];     // (262144, 8) int32
    const float* w    = (const float*)d_in[2];   // (262144, 8) fp32
    float*       out  = (float*)d_out;           // (64, 262144) fp32

    const size_t xt_bytes = (size_t)IN_N * BATCH * sizeof(float);  // 64 MiB

    if (ws_size >= xt_bytes) {
        float* xt = (float*)d_ws;
        transpose_kernel<<<IN_N / 64, 256, 0, stream>>>(inp, xt);
        dim3 grid(OUT_N / 32, 2);
        gather_kernel<<<grid, 256, 0, stream>>>(xt, conn, w, out);
    } else {
        direct_kernel<<<OUT_N / 256, 256, 0, stream>>>(inp, conn, w, out);
    }
}

// Round 4
// 222.689 us; speedup vs baseline: 1.3273x; 1.0114x over previous
//
#include <hip/hip_runtime.h>

// PositionalSparseLinear2d: out[b,o] = sum_k input[b, conn[o,k]] * weights[o,k]
// B=64, N_in = N_out = 512*512 = 262144, K=8, all fp32.

#define IN_N  (512*512)
#define OUT_N (512*512)
#define BATCH 64
#define KCONN 8
#define TIDX  128   // idx-columns per transpose tile

// ---------------------------------------------------------------------------
// Kernel 1: transpose input (BATCH, IN_N) -> x_t (IN_N, BATCH).
// 128-idx x 64-batch tile, 256 threads, 8 float4 loads + 8 float4 stores per
// thread (high MLP). Reads: wave covers 2 batch-rows x 512 B contiguous.
// Writes: wave covers 4 idx-rows x 256 B = 1 KB contiguous. LDS [64][129]:
// store-side 2-way bank alias (free), read-side stride 129 floats -> banks
// step 4 across lanes -> 2-way (free).
// ---------------------------------------------------------------------------
__global__ __launch_bounds__(256) void transpose_kernel(const float* __restrict__ in,
                                                        float* __restrict__ xt) {
    __shared__ float lds[BATCH][TIDX + 1];   // 64 x 129 x 4 B = 33 KB
    const int t    = threadIdx.x;
    const int idx0 = blockIdx.x * TIDX;

    // Load: 64 rows x 128 floats. Pass p: row b = p*8 + (t>>5), 32 lanes x
    // float4 cover the 512 B row.
    const int lb = t >> 5;          // 0..7
    const int lc = (t & 31) << 2;   // 0,4,...,124
#pragma unroll
    for (int p = 0; p < 8; ++p) {
        const int b = p * 8 + lb;
        float4 v = *(const float4*)(in + (size_t)b * IN_N + idx0 + lc);
        lds[b][lc + 0] = v.x;
        lds[b][lc + 1] = v.y;
        lds[b][lc + 2] = v.z;
        lds[b][lc + 3] = v.w;
    }
    __syncthreads();

    // Store: 128 idx-rows x 64 floats. Pass p: idx i = p*16 + (t>>4), 16
    // lanes x float4 cover the 256 B row.
    const int si = t >> 4;          // 0..15
    const int sb = (t & 15) << 2;   // 0,4,...,60
#pragma unroll
    for (int p = 0; p < 8; ++p) {
        const int i = p * 16 + si;
        float4 u;
        u.x = lds[sb + 0][i];
        u.y = lds[sb + 1][i];
        u.z = lds[sb + 2][i];
        u.w = lds[sb + 3][i];
        *(float4*)(xt + (size_t)(idx0 + i) * BATCH + sb) = u;
    }
}

// ---------------------------------------------------------------------------
// Kernel 2: K-split gather. Thread = (o, k, 32-batch half). Each thread
// issues 8 independent float4 loads (its 128 B half-row -- 2 adjacent cache
// lines), scales by its weight, then the 8 k-lanes (low 3 bits of the lane
// id) reduce-scatter via __shfl_xor in 3 steps; lane k ends with 4 batch
// sums and stores them. VGPR ~24 -> high occupancy; ~8 loads in flight/wave.
// ---------------------------------------------------------------------------
__global__ __launch_bounds__(256) void gather_kernel(const float* __restrict__ xt,
                                                     const int* __restrict__ conn,
                                                     const float* __restrict__ w,
                                                     float* __restrict__ out) {
    const int t  = threadIdx.x;
    const int o0 = blockIdx.x * 32;          // 32 outputs per block
    const int h  = blockIdx.y * 32;          // batch half: 0 or 32
    const int g  = o0 * KCONN + t;           // coalesced conn/w index
    const int k  = t & 7;
    const int o  = o0 + (t >> 3);

    const int   ci = conn[g];
    const float wv = w[g];

    // 8 independent line-loads: the full 128 B half-row for this (o,k).
    const float4* row = (const float4*)(xt + (size_t)ci * BATCH + h);
    float4 r[8];
#pragma unroll
    for (int q = 0; q < 8; ++q) r[q] = row[q];

    float cur[32];
#pragma unroll
    for (int q = 0; q < 8; ++q) {
        cur[q * 4 + 0] = r[q].x * wv;
        cur[q * 4 + 1] = r[q].y * wv;
        cur[q * 4 + 2] = r[q].z * wv;
        cur[q * 4 + 3] = r[q].w * wv;
    }

    // Reduce-scatter over the 8 k-lanes; bsel tracks the kept batch window.
    int bsel = 0;

    {   // step m=1, n=32
        const bool up = (k & 1) != 0;
        float nxt[16];
#pragma unroll
        for (int j = 0; j < 16; ++j) {
            float send = up ? cur[j] : cur[j + 16];
            float keep = up ? cur[j + 16] : cur[j];
            nxt[j] = keep + __shfl_xor(send, 1, 64);
        }
#pragma unroll
        for (int j = 0; j < 16; ++j) cur[j] = nxt[j];
        if (up) bsel += 16;
    }
    {   // step m=2, n=16
        const bool up = (k & 2) != 0;
        float nxt[8];
#pragma unroll
        for (int j = 0; j < 8; ++j) {
            float send = up ? cur[j] : cur[j + 8];
            float keep = up ? cur[j + 8] : cur[j];
            nxt[j] = keep + __shfl_xor(send, 2, 64);
        }
#pragma unroll
        for (int j = 0; j < 8; ++j) cur[j] = nxt[j];
        if (up) bsel += 8;
    }
    {   // step m=4, n=8
        const bool up = (k & 4) != 0;
        float nxt[4];
#pragma unroll
        for (int j = 0; j < 4; ++j) {
            float send = up ? cur[j] : cur[j + 4];
            float keep = up ? cur[j + 4] : cur[j];
            nxt[j] = keep + __shfl_xor(send, 4, 64);
        }
#pragma unroll
        for (int j = 0; j < 4; ++j) cur[j] = nxt[j];
        if (up) bsel += 4;
    }

    // lane holds the full k-sum for batches b = h + bsel + 0..3
#pragma unroll
    for (int j = 0; j < 4; ++j) {
        out[(size_t)(h + bsel + j) * OUT_N + o] = cur[j];
    }
}

// ---------------------------------------------------------------------------
// Fallback (only if workspace is too small for the 64 MiB transposed copy):
// direct gather on the original layout. Correct but cache-line-wasteful.
// ---------------------------------------------------------------------------
__global__ __launch_bounds__(256) void direct_kernel(const float* __restrict__ in,
                                                     const int* __restrict__ conn,
                                                     const float* __restrict__ w,
                                                     float* __restrict__ out) {
    const int o = blockIdx.x * 256 + threadIdx.x;

    const int4   c0 = ((const int4*)conn)[(size_t)o * 2 + 0];
    const int4   c1 = ((const int4*)conn)[(size_t)o * 2 + 1];
    const float4 w0 = ((const float4*)w)[(size_t)o * 2 + 0];
    const float4 w1 = ((const float4*)w)[(size_t)o * 2 + 1];

    const int   cidx[KCONN] = {c0.x, c0.y, c0.z, c0.w, c1.x, c1.y, c1.z, c1.w};
    const float wk[KCONN]   = {w0.x, w0.y, w0.z, w0.w, w1.x, w1.y, w1.z, w1.w};

    for (int b = 0; b < BATCH; ++b) {
        const float* xb = in + (size_t)b * IN_N;
        float acc = 0.0f;
#pragma unroll
        for (int k = 0; k < KCONN; ++k) acc += xb[cidx[k]] * wk[k];
        out[(size_t)b * OUT_N + o] = acc;
    }
}

extern "C" void kernel_launch(void* const* d_in, const int* in_sizes, int n_in,
                              void* d_out, int out_size, void* d_ws, size_t ws_size,
                              hipStream_t stream) {
    const float* inp  = (const float*)d_in[0];   // (64, 512, 512) fp32
    const int*   conn = (const int*)d_in[1];     // (262144, 8) int32
    const float* w    = (const float*)d_in[2];   // (262144, 8) fp32
    float*       out  = (float*)d_out;           // (64, 262144) fp32

    const size_t xt_bytes = (size_t)IN_N * BATCH * sizeof(float);  // 64 MiB

    if (ws_size >= xt_bytes) {
        float* xt = (float*)d_ws;
        transpose_kernel<<<IN_N / TIDX, 256, 0, stream>>>(inp, xt);
        dim3 grid(OUT_N / 32, 2);
        gather_kernel<<<grid, 256, 0, stream>>>(xt, conn, w, out);
    } else {
        direct_kernel<<<OUT_N / 256, 256, 0, stream>>>(inp, conn, w, out);
    }
}